// Round 8
// baseline (282.486 us; speedup 1.0000x reference)
//
#include <hip/hip_runtime.h>

// modConv: y = demod(b,fo) * conv3x3(x * s(b,fi), w * w_scale)
// bf16 MFMA implicit GEMM (M=fo, N=pixels, K=fi, 9 taps accumulated).
// R13: resubmission of R12 (round-7 bench died at container level; audit
//     found no kernel defect: barriers uniform, dbuf rotation race-free,
//     vmcnt retirement conservative).
//     R12: barrier-minimal schedule. Wave tile resplit 128fo x 64px -> 64fo x
//     128px (2x2); w A-frags go global->REGISTERS (dbuf, 1 phase ahead,
//     compiler auto-vmcnt) so w has NO cross-wave dependency -> the per-phase
//     barrier (144x) is deleted; only 1 barrier per gc (16 total) for the
//     x LDS double-buffer rotation. x B-frags via ds_read_b128 (8/wave-phase).
//     x staged at phases 3-5 (4-6 phase slack). 18-phase (2-gc) superloop
//     keeps LDS offsets + A-reg parity compile-time.

typedef __bf16 bf16_t;
typedef __bf16 bf16x8 __attribute__((ext_vector_type(8)));
typedef float floatx4 __attribute__((ext_vector_type(4)));

#define HW_ 4096
#define FCSCALE 0.04419417382415922f   /* 512^-0.5 */
#define WSCALE  0.014731391274719742f  /* (512*9)^-0.5 */

#define VMCNT(n) asm volatile("s_waitcnt vmcnt(" #n ")" ::: "memory")

__device__ __forceinline__ void gload_lds16(const bf16_t* g, bf16_t* l) {
  __builtin_amdgcn_global_load_lds(
      (const __attribute__((address_space(1))) void*)g,
      (__attribute__((address_space(3))) void*)l, 16, 0, 0);
}

// ---- prep bodies (R10-verified) ----

__device__ __forceinline__ void style_body(int bid, int t,
    const float* __restrict__ style, const float* __restrict__ fc_w,
    const float* __restrict__ fc_b, float* __restrict__ s_out) {
  int o = bid * 4 + (t >> 6);                   // 0..4095 = b*512+fi
  int lane = t & 63;
  int b = o >> 9, fi = o & 511;
  const float4* st = (const float4*)(style + b * 512);
  const float4* fw = (const float4*)(fc_w + (size_t)fi * 512);
  float4 a0 = st[lane * 2],     w0 = fw[lane * 2];
  float4 a1 = st[lane * 2 + 1], w1 = fw[lane * 2 + 1];
  float acc = a0.x * w0.x + a0.y * w0.y + a0.z * w0.z + a0.w * w0.w
            + a1.x * w1.x + a1.y * w1.y + a1.z * w1.z + a1.w * w1.w;
#pragma unroll
  for (int d = 32; d >= 1; d >>= 1) acc += __shfl_xor(acc, d, 64);
  if (lane == 0) s_out[o] = acc * FCSCALE + fc_b[fi];
}

__device__ __forceinline__ void wsq_wt_body(int bid, int t,
    const float* __restrict__ w, float* __restrict__ wsq, bf16_t* __restrict__ wt) {
  int idx = bid * 256 + t;                      // fo*512+fi
  int fo = idx >> 9, fi = idx & 511;
  const float* wp = w + (size_t)idx * 9;
  float v[9], q = 0.f;
#pragma unroll
  for (int k = 0; k < 9; ++k) { v[k] = wp[k] * WSCALE; q += v[k] * v[k]; }
  wsq[idx] = q;
#pragma unroll
  for (int k = 0; k < 9; ++k)
    wt[((((size_t)k * 64) + (fi >> 3)) * 512 + fo) * 8 + (fi & 7)] = (bf16_t)v[k];
}

__device__ __forceinline__ void demod_body(int bid, int t,
    const float* __restrict__ wsq, const float* __restrict__ s,
    float* __restrict__ dcoef) {
  int o = bid * 4 + (t >> 6);                   // 0..4095 = b*512+fo
  int lane = t & 63;
  int b = o >> 9, fo = o & 511;
  const float4* wq = (const float4*)(wsq + (size_t)fo * 512);
  const float4* sp = (const float4*)(s + b * 512);
  float acc = 0.f;
#pragma unroll
  for (int i = 0; i < 2; ++i) {
    float4 q = wq[lane * 2 + i], sv = sp[lane * 2 + i];
    acc += q.x * sv.x * sv.x + q.y * sv.y * sv.y + q.z * sv.z * sv.z + q.w * sv.w * sv.w;
  }
#pragma unroll
  for (int d = 32; d >= 1; d >>= 1) acc += __shfl_xor(acc, d, 64);
  if (lane == 0) dcoef[o] = rsqrtf(acc + 1e-8f);
}

// K1: blocks 0..1023 -> wsq_wt, 1024..2047 -> style, 2048 -> zerobuf
__global__ void k_prep1(const float* __restrict__ style, const float* __restrict__ fc_w,
                        const float* __restrict__ fc_b, const float* __restrict__ w,
                        float* __restrict__ s_out, float* __restrict__ wsq,
                        bf16_t* __restrict__ wt, bf16_t* __restrict__ zerobuf) {
  int blk = blockIdx.x, t = threadIdx.x;
  if (blk < 1024) {
    wsq_wt_body(blk, t, w, wsq, wt);
  } else if (blk < 2048) {
    style_body(blk - 1024, t, style, fc_w, fc_b, s_out);
  } else {
    if (t < 128) zerobuf[t] = (bf16_t)0.f;      // 256 B
  }
}

// xT[b][h][g][w][8] = bf16(x[b][g*8+j][h][w] * s)   (granule-major rows)
__device__ __forceinline__ void modx_body(int fi0, int h, int b, int t,
    const float* __restrict__ x, const float* __restrict__ s,
    bf16_t* __restrict__ xT, float (*tile)[65]) {
  int c4 = (t & 15) * 4, fr = t >> 4;            // float4 coalesced reads
#pragma unroll
  for (int i = 0; i < 2; ++i) {
    int fi_l = i * 16 + fr;
    float sv = s[b * 512 + fi0 + fi_l];
    float4 v = *(const float4*)(x + ((size_t)(b * 512 + fi0 + fi_l)) * HW_ + h * 64 + c4);
    tile[fi_l][c4] = v.x * sv; tile[fi_l][c4 + 1] = v.y * sv;
    tile[fi_l][c4 + 2] = v.z * sv; tile[fi_l][c4 + 3] = v.w * sv;
  }
  __syncthreads();
  int g_l = t >> 6, wcol = t & 63;               // write granule (g_l) x col
  bf16x8 vv;
#pragma unroll
  for (int j = 0; j < 8; ++j) vv[j] = (bf16_t)tile[g_l * 8 + j][wcol];
  *(bf16x8*)&xT[((((size_t)(b * 64 + h)) * 64 + (fi0 >> 3) + g_l) * 64 + wcol) * 8] = vv;
}

// K2: blocks 0..1023 -> demod, 1024..9215 -> modx
__global__ void k_prep2(const float* __restrict__ x, const float* __restrict__ s,
                        const float* __restrict__ wsq, float* __restrict__ dcoef,
                        bf16_t* __restrict__ xT) {
  __shared__ float tile[32][65];
  int blk = blockIdx.x, t = threadIdx.x;
  if (blk < 1024) {
    demod_body(blk, t, wsq, s, dcoef);
  } else {
    int m = blk - 1024;                          // 0..8191
    int b = m >> 10, rem = m & 1023;             // b 0..7
    int h = rem >> 4, fi0 = (rem & 15) * 32;
    modx_body(fi0, h, b, t, x, s, xT, tile);
  }
}

// ---- main conv ----
// LDS (bf16 elems): [0,24576) = x bufs 2 x [6 r][4 g][64 c][8 fi]; [24576,24584)
// = zero slot. Block = 128 fo x 256 px (4 rows h0..h0+3), 4 waves in 2x2 split:
// wave = 64 fo ((wv&1)*64) x 128 px (rows rowpair..rowpair+1). 144 its = 16 gc
// x 9 taps, as 8 superloops of 18 phases (2 gc). Per phase: [x-stage part if
// tap 3..5] + 4 A-frag global->reg loads (it+1, dbuf, compiler auto-vmcnt) +
// 8 B-frag ds_read_b128 + 32 MFMA. One barrier per gc (x dbuf rotation) with
// pre-barrier VMCNT(4) (drain own x staging, keep A(it+1) in flight).
__global__ __launch_bounds__(256, 2) void k_conv(const bf16_t* __restrict__ wt,
                                                 const bf16_t* __restrict__ xT,
                                                 const float* __restrict__ dcoef,
                                                 const bf16_t* __restrict__ zerobuf,
                                                 float* __restrict__ out) {
  __shared__ __align__(16) bf16_t sh[24584];     // 49168 B

  int b   = blockIdx.x;                 // 0..7  (linear%8=b -> XCD-pinned batch)
  int foB = blockIdx.y;                 // 0..3
  int hq  = blockIdx.z;                 // 0..15 -> rows h0..h0+3
  int t = threadIdx.x;
  int wv = t >> 6, lane = t & 63, quad = lane >> 4, l16 = lane & 15;
  int h0 = hq * 4;
  int rowpair = (wv >> 1) * 2;                   // 0 or 2: wave's px row pair
  int foW = foB * 128 + (wv & 1) * 64;           // wave's 64-fo slice

  const bf16_t* xTb = xT + (size_t)b * 64 * 64 * 64 * 8;   // [h][g][w][8]
  const bf16_t* wA_base = wt + ((size_t)(quad * 512 + foW + l16)) * 8;
  const bf16_t* xlbase = &sh[(quad * 64 + l16) * 8];
  const bf16_t* zslotp = &sh[24576];

  floatx4 acc[4][8];
#pragma unroll
  for (int i = 0; i < 4; ++i)
#pragma unroll
    for (int j = 0; j < 8; ++j) acc[i][j] = (floatx4){0.f, 0.f, 0.f, 0.f};

  bf16x8 aF[2][4];

  // ---- prologue: zero slot, stage x(gc0)->buf0, load A(it=0)->aF[0]
  if (t < 8) sh[24576 + t] = (bf16_t)0.f;
#pragma unroll
  for (int part = 0; part < 3; ++part)
#pragma unroll
    for (int u = 0; u < 2; ++u) {
      int sp = part * 8 + wv * 2 + u;            // 0..23 spans
      int r = sp >> 2, g = sp & 3;
      int rg = h0 + r - 1;
      const bf16_t* src = ((unsigned)rg < 64u)
          ? xTb + (((size_t)rg * 64 + g) * 64 + lane) * 8
          : zerobuf;
      gload_lds16(src, &sh[((r * 4 + g) * 64) * 8]);
    }
#pragma unroll
  for (int i = 0; i < 4; ++i)
    aF[0][i] = *(const bf16x8*)(wA_base + i * 128);
  VMCNT(0);
  __syncthreads();

#define PH(IT18, LAST)                                                         \
  do {                                                                         \
    const int TAP_ = (IT18) % 9;                                               \
    const int GH_  = (IT18) / 9;                                               \
    if ((IT18) == 0 || (IT18) == 9) {                                          \
      VMCNT(4);                            /* drain own x staging */           \
      __builtin_amdgcn_s_barrier();        /* x dbuf rotation point */         \
      __builtin_amdgcn_sched_barrier(0);                                       \
    }                                                                          \
    if (TAP_ >= 3 && TAP_ <= 5 && !((LAST) && GH_ == 1)) {                     \
      int gcn = gbase + GH_ + 1;           /* stage x(gcn) -> buf gcn&1 */     \
      int xb1 = (gcn & 1) * 12288;                                             \
      _Pragma("unroll")                                                        \
      for (int u = 0; u < 2; ++u) {                                            \
        int sp = (TAP_ - 3) * 8 + wv * 2 + u;                                  \
        int r = sp >> 2, g = sp & 3;                                           \
        int rg = h0 + r - 1;                                                   \
        const bf16_t* src = ((unsigned)rg < 64u)                               \
            ? xTb + (((size_t)rg * 64 + gcn * 4 + g) * 64 + lane) * 8          \
            : zerobuf;                                                         \
        gload_lds16(src, &sh[xb1 + ((r * 4 + g) * 64) * 8]);                   \
      }                                                                        \
    }                                                                          \
    if (!((LAST) && (IT18) == 17)) {       /* A(it+1) -> other reg set */      \
      const int T1 = ((IT18) + 1) % 9;                                         \
      const int C1 = ((IT18) + 1) / 9;                                         \
      const bf16_t* pA = wA_base + (size_t)(T1 * 64 + (gbase + C1) * 4) * 4096;\
      _Pragma("unroll")                                                        \
      for (int i = 0; i < 4; ++i)                                              \
        aF[((IT18) + 1) & 1][i] = *(const bf16x8*)(pA + i * 128);              \
    }                                                                          \
    {                                      /* compute(it = 18*gcp + IT18) */   \
      const int KH_ = TAP_ / 3, KW_ = TAP_ % 3;                                \
      const int XO_ = GH_ * 12288;                                             \
      __builtin_amdgcn_s_setprio(1);                                           \
      _Pragma("unroll")                                                        \
      for (int j = 0; j < 8; ++j) {                                            \
        int r = rowpair + (j >> 2) + KH_;                                      \
        const bf16_t* ap =                                                     \
            xlbase + XO_ + r * 2048 + ((j & 3) * 16 + KW_ - 1) * 8;            \
        if (KW_ == 0 && (j & 3) == 0) { if (l16 == 0)  ap = zslotp; }          \
        if (KW_ == 2 && (j & 3) == 3) { if (l16 == 15) ap = zslotp; }          \
        bf16x8 bfr = *(const bf16x8*)ap;                                       \
        _Pragma("unroll")                                                      \
        for (int i = 0; i < 4; ++i)                                            \
          acc[i][j] = __builtin_amdgcn_mfma_f32_16x16x32_bf16(                 \
              aF[(IT18) & 1][i], bfr, acc[i][j], 0, 0, 0);                     \
      }                                                                        \
      __builtin_amdgcn_s_setprio(0);                                           \
    }                                                                          \
  } while (0)

  for (int gcp = 0; gcp < 7; ++gcp) {
    int gbase = gcp * 2;
    PH(0, false);  PH(1, false);  PH(2, false);  PH(3, false);  PH(4, false);
    PH(5, false);  PH(6, false);  PH(7, false);  PH(8, false);  PH(9, false);
    PH(10, false); PH(11, false); PH(12, false); PH(13, false); PH(14, false);
    PH(15, false); PH(16, false); PH(17, false);
  }
  {
    int gbase = 14;
    PH(0, true);  PH(1, true);  PH(2, true);  PH(3, true);  PH(4, true);
    PH(5, true);  PH(6, true);  PH(7, true);  PH(8, true);  PH(9, true);
    PH(10, true); PH(11, true); PH(12, true); PH(13, true); PH(14, true);
    PH(15, true); PH(16, true); PH(17, true);
  }
#undef PH

  // epilogue: C/D col=l16 (n=px within Ntile), row=quad*4+rr (m=fo in Mtile)
#pragma unroll
  for (int i = 0; i < 4; ++i) {
#pragma unroll
    for (int rr = 0; rr < 4; ++rr) {
      int fo_g = foW + i * 16 + quad * 4 + rr;
      float dm = dcoef[b * 512 + fo_g];
      float* op = out + ((size_t)(b * 512 + fo_g)) * 4096;
#pragma unroll
      for (int j = 0; j < 8; ++j) {
        int h = h0 + rowpair + (j >> 2);
        int c = (j & 3) * 16 + l16;
        op[h * 64 + c] = acc[i][j][rr] * dm;
      }
    }
  }
}

extern "C" void kernel_launch(void* const* d_in, const int* in_sizes, int n_in,
                              void* d_out, int out_size, void* d_ws, size_t ws_size,
                              hipStream_t stream) {
  const float* x     = (const float*)d_in[0];
  const float* style = (const float*)d_in[1];
  const float* w     = (const float*)d_in[2];
  const float* fc_w  = (const float*)d_in[3];
  const float* fc_b  = (const float*)d_in[4];
  float* out = (float*)d_out;
  char* ws = (char*)d_ws;

  float*  s       = (float*)(ws);                  // 16 KB
  float*  dcoef   = (float*)(ws + 16384);          // 16 KB
  float*  wsq     = (float*)(ws + 32768);          // 1 MB
  bf16_t* zerobuf = (bf16_t*)(ws + 1081344);       // 256 B of zeros
  bf16_t* wt      = (bf16_t*)(ws + 1081600);       // 4.5 MB  [tap][g][fo][8]
  bf16_t* xT      = (bf16_t*)(ws + 5800192);       // 32 MB   [b][h][g][w][8]

  k_prep1<<<2049, 256, 0, stream>>>(style, fc_w, fc_b, w, s, wsq, wt, zerobuf);
  k_prep2<<<9216, 256, 0, stream>>>(x, s, wsq, dcoef, xT);
  // grid.x = b -> linear block id % 8 == b -> XCD-pinned batch slice
  k_conv<<<dim3(8, 4, 16), 256, 0, stream>>>(wt, xT, dcoef, zerobuf, out);
}

// Round 10
// 235.603 us; speedup vs baseline: 1.1990x; 1.1990x over previous
//
#include <hip/hip_runtime.h>

// modConv: y = demod(b,fo) * conv3x3(x * s(b,fi), w * w_scale)
// bf16 MFMA implicit GEMM (M=fo, N=pixels, K=fi, 9 taps accumulated).
// R15: resubmission of R14 (round-9 bench died at container level; full
//     schedule trace found no defect: pair-buf parity, vmcnt drains, dbuf
//     rotation, cross-wave LDS hazards, addressing all verified).
//     R14: R11 geometry (128fo x 64px waves, A from LDS, no spill) +
//     half-rate barrier schedule: w staged in PAIRS (tiles p+2,p+3) at even
//     phases into 2x16KB pair-buffers (2-phase lead), barrier only at even
//     phases (72 vs 144), counted vmcnt that never drains fresh loads; odd
//     phases are pure compute. Zero-slot replaced by cndmask edge zeroing so
//     LDS = x 48KB + w 32KB = 80KB exactly (2 blocks/CU).

typedef __bf16 bf16_t;
typedef __bf16 bf16x8 __attribute__((ext_vector_type(8)));
typedef float floatx4 __attribute__((ext_vector_type(4)));

#define HW_ 4096
#define FCSCALE 0.04419417382415922f   /* 512^-0.5 */
#define WSCALE  0.014731391274719742f  /* (512*9)^-0.5 */

#define VMCNT(n) asm volatile("s_waitcnt vmcnt(" #n ")" ::: "memory")

__device__ __forceinline__ void gload_lds16(const bf16_t* g, bf16_t* l) {
  __builtin_amdgcn_global_load_lds(
      (const __attribute__((address_space(1))) void*)g,
      (__attribute__((address_space(3))) void*)l, 16, 0, 0);
}

// ---- prep bodies (R10-verified) ----

__device__ __forceinline__ void style_body(int bid, int t,
    const float* __restrict__ style, const float* __restrict__ fc_w,
    const float* __restrict__ fc_b, float* __restrict__ s_out) {
  int o = bid * 4 + (t >> 6);                   // 0..4095 = b*512+fi
  int lane = t & 63;
  int b = o >> 9, fi = o & 511;
  const float4* st = (const float4*)(style + b * 512);
  const float4* fw = (const float4*)(fc_w + (size_t)fi * 512);
  float4 a0 = st[lane * 2],     w0 = fw[lane * 2];
  float4 a1 = st[lane * 2 + 1], w1 = fw[lane * 2 + 1];
  float acc = a0.x * w0.x + a0.y * w0.y + a0.z * w0.z + a0.w * w0.w
            + a1.x * w1.x + a1.y * w1.y + a1.z * w1.z + a1.w * w1.w;
#pragma unroll
  for (int d = 32; d >= 1; d >>= 1) acc += __shfl_xor(acc, d, 64);
  if (lane == 0) s_out[o] = acc * FCSCALE + fc_b[fi];
}

__device__ __forceinline__ void wsq_wt_body(int bid, int t,
    const float* __restrict__ w, float* __restrict__ wsq, bf16_t* __restrict__ wt) {
  int idx = bid * 256 + t;                      // fo*512+fi
  int fo = idx >> 9, fi = idx & 511;
  const float* wp = w + (size_t)idx * 9;
  float v[9], q = 0.f;
#pragma unroll
  for (int k = 0; k < 9; ++k) { v[k] = wp[k] * WSCALE; q += v[k] * v[k]; }
  wsq[idx] = q;
#pragma unroll
  for (int k = 0; k < 9; ++k)
    wt[((((size_t)k * 64) + (fi >> 3)) * 512 + fo) * 8 + (fi & 7)] = (bf16_t)v[k];
}

__device__ __forceinline__ void demod_body(int bid, int t,
    const float* __restrict__ wsq, const float* __restrict__ s,
    float* __restrict__ dcoef) {
  int o = bid * 4 + (t >> 6);                   // 0..4095 = b*512+fo
  int lane = t & 63;
  int b = o >> 9, fo = o & 511;
  const float4* wq = (const float4*)(wsq + (size_t)fo * 512);
  const float4* sp = (const float4*)(s + b * 512);
  float acc = 0.f;
#pragma unroll
  for (int i = 0; i < 2; ++i) {
    float4 q = wq[lane * 2 + i], sv = sp[lane * 2 + i];
    acc += q.x * sv.x * sv.x + q.y * sv.y * sv.y + q.z * sv.z * sv.z + q.w * sv.w * sv.w;
  }
#pragma unroll
  for (int d = 32; d >= 1; d >>= 1) acc += __shfl_xor(acc, d, 64);
  if (lane == 0) dcoef[o] = rsqrtf(acc + 1e-8f);
}

// K1: blocks 0..1023 -> wsq_wt, 1024..2047 -> style, 2048 -> zerobuf
__global__ void k_prep1(const float* __restrict__ style, const float* __restrict__ fc_w,
                        const float* __restrict__ fc_b, const float* __restrict__ w,
                        float* __restrict__ s_out, float* __restrict__ wsq,
                        bf16_t* __restrict__ wt, bf16_t* __restrict__ zerobuf) {
  int blk = blockIdx.x, t = threadIdx.x;
  if (blk < 1024) {
    wsq_wt_body(blk, t, w, wsq, wt);
  } else if (blk < 2048) {
    style_body(blk - 1024, t, style, fc_w, fc_b, s_out);
  } else {
    if (t < 128) zerobuf[t] = (bf16_t)0.f;      // 256 B
  }
}

// xT[b][h][g][w][8] = bf16(x[b][g*8+j][h][w] * s)   (granule-major rows)
__device__ __forceinline__ void modx_body(int fi0, int h, int b, int t,
    const float* __restrict__ x, const float* __restrict__ s,
    bf16_t* __restrict__ xT, float (*tile)[65]) {
  int c4 = (t & 15) * 4, fr = t >> 4;            // float4 coalesced reads
#pragma unroll
  for (int i = 0; i < 2; ++i) {
    int fi_l = i * 16 + fr;
    float sv = s[b * 512 + fi0 + fi_l];
    float4 v = *(const float4*)(x + ((size_t)(b * 512 + fi0 + fi_l)) * HW_ + h * 64 + c4);
    tile[fi_l][c4] = v.x * sv; tile[fi_l][c4 + 1] = v.y * sv;
    tile[fi_l][c4 + 2] = v.z * sv; tile[fi_l][c4 + 3] = v.w * sv;
  }
  __syncthreads();
  int g_l = t >> 6, wcol = t & 63;               // write granule (g_l) x col
  bf16x8 vv;
#pragma unroll
  for (int j = 0; j < 8; ++j) vv[j] = (bf16_t)tile[g_l * 8 + j][wcol];
  *(bf16x8*)&xT[((((size_t)(b * 64 + h)) * 64 + (fi0 >> 3) + g_l) * 64 + wcol) * 8] = vv;
}

// K2: blocks 0..1023 -> demod, 1024..9215 -> modx
__global__ void k_prep2(const float* __restrict__ x, const float* __restrict__ s,
                        const float* __restrict__ wsq, float* __restrict__ dcoef,
                        bf16_t* __restrict__ xT) {
  __shared__ float tile[32][65];
  int blk = blockIdx.x, t = threadIdx.x;
  if (blk < 1024) {
    demod_body(blk, t, wsq, s, dcoef);
  } else {
    int m = blk - 1024;                          // 0..8191
    int b = m >> 10, rem = m & 1023;             // b 0..7
    int h = rem >> 4, fi0 = (rem & 15) * 32;
    modx_body(fi0, h, b, t, x, s, xT, tile);
  }
}

// ---- main conv ----
// LDS (bf16 elems): [0,24576) x bufs 2 x [6 r][4 g][64 c][8]; [24576,40960)
// w pair-bufs 2 x {tile0 4096, tile1 4096}. Total 81920 B (2 blocks/CU).
// Block = 128 fo x 256 px (4 rows h0..h0+3), 4 waves (wave = 128fo x 64px row
// h0+wv). 144 its = 16 gc x 9 taps, 18-phase superloops (2 gc).
// Even phase p: VMCNT(N_p) [N = x-loads issued after needed w-pair -> never
// drains fresh loads]; s_barrier; sched_barrier; stage w-pair(p+2,p+3)
// [4 gloads]; [x part]; compute. Odd phase: no wait/barrier; [x part]; compute.
// w pair-buf parity = (gcp&1) ^ ((p>>1)&1) -- static offset XOR runtime sel.
__global__ __launch_bounds__(256, 2) void k_conv(const bf16_t* __restrict__ wt,
                                                 const bf16_t* __restrict__ xT,
                                                 const float* __restrict__ dcoef,
                                                 const bf16_t* __restrict__ zerobuf,
                                                 float* __restrict__ out) {
  __shared__ __align__(16) bf16_t sh[40960];     // 81920 B exactly

  int b   = blockIdx.x;                 // 0..7  (linear%8=b -> XCD-pinned batch)
  int foB = blockIdx.y;                 // 0..3
  int hq  = blockIdx.z;                 // 0..15 -> rows h0..h0+3
  int t = threadIdx.x;
  int wv = t >> 6, lane = t & 63, quad = lane >> 4, l16 = lane & 15;
  int h0 = hq * 4;
  int fo_l = t & 127, chunk_hi = t >> 7;

  const bf16_t* xTb = xT + (size_t)b * 64 * 64 * 64 * 8;   // [h][g][w][8]
  int XRB = ((wv * 4 + quad) * 64 + l16) * 8;    // x frag base: r=wv,g=quad,c=l16

  floatx4 acc[8][4];
#pragma unroll
  for (int i = 0; i < 8; ++i)
#pragma unroll
    for (int j = 0; j < 4; ++j) acc[i][j] = (floatx4){0.f, 0.f, 0.f, 0.f};

  bf16x8 z8;
#pragma unroll
  for (int q = 0; q < 8; ++q) z8[q] = (bf16_t)0.f;

  // ---- prologue: stage x(gc0)->buf0 (6 gloads), w pair0 (w0,w1) -> buf0
#pragma unroll
  for (int part = 0; part < 3; ++part)
#pragma unroll
    for (int u = 0; u < 2; ++u) {
      int sp = part * 8 + wv * 2 + u;            // 0..23 spans
      int r = sp >> 2, g = sp & 3;
      int rg = h0 + r - 1;
      const bf16_t* src = ((unsigned)rg < 64u)
          ? xTb + (((size_t)rg * 64 + g) * 64 + lane) * 8
          : zerobuf;
      gload_lds16(src, &sh[((r * 4 + g) * 64) * 8]);
    }
#pragma unroll
  for (int half = 0; half < 2; ++half)           // w(0)=tap0, w(1)=tap1, gc0
#pragma unroll
    for (int itw = 0; itw < 2; ++itw) {
      int cw = itw * 2 + chunk_hi;
      gload_lds16(wt + ((((size_t)half * 64) + cw) * 512 + foB * 128 + fo_l) * 8,
                  &sh[24576 + half * 4096 + (itw * 256 + wv * 64) * 8]);
    }
  VMCNT(0);
  __syncthreads();

#define PH(P, NW, XPART, WST)                                                  \
  do {                                                                         \
    const int TAP_ = (P) % 9;                                                  \
    const int GH_  = (P) / 9;                                                  \
    if (((P) & 1) == 0) {                                                      \
      VMCNT(NW);                                                               \
      __builtin_amdgcn_s_barrier();                                            \
      __builtin_amdgcn_sched_barrier(0);                                       \
    }                                                                          \
    if (WST) {                            /* stage w pair (it+2, it+3) */      \
      int wbo = 24576 + ((wsel ^ (((P) >> 1) & 1) ^ 1)) * 8192;                \
      _Pragma("unroll")                                                        \
      for (int half = 0; half < 2; ++half) {                                   \
        const int PP = (P) + 2 + half;                                         \
        const int T2 = PP % 9;                                                 \
        const int GA = PP / 9;                                                 \
        _Pragma("unroll")                                                      \
        for (int itw = 0; itw < 2; ++itw) {                                    \
          int cw = itw * 2 + chunk_hi;                                         \
          gload_lds16(wt + ((((size_t)T2 * 64) + (gbase + GA) * 4 + cw) * 512  \
                            + foB * 128 + fo_l) * 8,                           \
                      &sh[wbo + half * 4096 + (itw * 256 + wv * 64) * 8]);     \
        }                                                                      \
      }                                                                        \
    }                                                                          \
    if ((XPART) >= 0) {                   /* stage x(gc+1) part */             \
      int gcn = gbase + GH_ + 1;                                               \
      int xb1 = (gcn & 1) * 12288;                                             \
      _Pragma("unroll")                                                        \
      for (int u = 0; u < 2; ++u) {                                            \
        int sp = (XPART) * 8 + wv * 2 + u;                                     \
        int r = sp >> 2, g = sp & 3;                                           \
        int rg = h0 + r - 1;                                                   \
        const bf16_t* src = ((unsigned)rg < 64u)                               \
            ? xTb + (((size_t)rg * 64 + gcn * 4 + g) * 64 + lane) * 8          \
            : zerobuf;                                                         \
        gload_lds16(src, &sh[xb1 + ((r * 4 + g) * 64) * 8]);                   \
      }                                                                        \
    }                                                                          \
    {                                     /* compute(it = 18*gcp + P) */       \
      const int KH_ = TAP_ / 3, KW_ = TAP_ % 3;                                \
      const int XO_ = GH_ * 12288;                                             \
      int wb = 24576 + (wsel ^ (((P) >> 1) & 1)) * 8192 + ((P) & 1) * 4096;    \
      bf16x8 bfr[4];                                                           \
      _Pragma("unroll")                                                        \
      for (int j = 0; j < 4; ++j) {                                            \
        if (KW_ == 0 && j == 0) {                                              \
          bfr[0] = *(const bf16x8*)&sh[XO_ +                                   \
              (((wv + KH_) * 4 + quad) * 64 + ((l16 + 63) & 63)) * 8];         \
          bfr[0] = (l16 == 0) ? z8 : bfr[0];                                   \
        } else if (KW_ == 2 && j == 3) {                                       \
          bfr[3] = *(const bf16x8*)&sh[XO_ +                                   \
              (((wv + KH_) * 4 + quad) * 64 + ((l16 + 49) & 63)) * 8];         \
          bfr[3] = (l16 == 15) ? z8 : bfr[3];                                  \
        } else {                                                               \
          bfr[j] = *(const bf16x8*)&sh[XRB + XO_ + KH_ * 2048 +                \
                                       (j * 16 + KW_ - 1) * 8];                \
        }                                                                      \
      }                                                                        \
      __builtin_amdgcn_s_setprio(1);                                           \
      _Pragma("unroll")                                                        \
      for (int i = 0; i < 8; ++i) {                                            \
        bf16x8 afr = *(const bf16x8*)&sh[wb + (quad * 128 + i * 16 + l16) * 8];\
        _Pragma("unroll")                                                      \
        for (int j = 0; j < 4; ++j)                                            \
          acc[i][j] = __builtin_amdgcn_mfma_f32_16x16x32_bf16(                 \
              afr, bfr[j], acc[i][j], 0, 0, 0);                                \
      }                                                                        \
      __builtin_amdgcn_s_setprio(0);                                           \
    }                                                                          \
  } while (0)

  for (int gcp = 0; gcp < 7; ++gcp) {
    int gbase = gcp * 2;
    int wsel = gcp & 1;
    PH(0, 0, -1, 1);  PH(1, 0, -1, 0);  PH(2, 0, -1, 1);  PH(3, 0, 0, 0);
    PH(4, 2, 1, 1);   PH(5, 0, 2, 0);   PH(6, 4, -1, 1);  PH(7, 0, -1, 0);
    PH(8, 0, -1, 1);  PH(9, 0, -1, 0);  PH(10, 0, -1, 1); PH(11, 0, -1, 0);
    PH(12, 0, 0, 1);  PH(13, 0, 1, 0);  PH(14, 4, 2, 1);  PH(15, 0, -1, 0);
    PH(16, 2, -1, 1); PH(17, 0, -1, 0);
  }
  {
    int gbase = 14;
    int wsel = 1;                                // gcp = 7
    PH(0, 0, -1, 1);  PH(1, 0, -1, 0);  PH(2, 0, -1, 1);  PH(3, 0, 0, 0);
    PH(4, 2, 1, 1);   PH(5, 0, 2, 0);   PH(6, 4, -1, 1);  PH(7, 0, -1, 0);
    PH(8, 0, -1, 1);  PH(9, 0, -1, 0);  PH(10, 0, -1, 1); PH(11, 0, -1, 0);
    PH(12, 0, -1, 1); PH(13, 0, -1, 0); PH(14, 0, -1, 1); PH(15, 0, -1, 0);
    PH(16, 0, -1, 0); PH(17, 0, -1, 0);
  }
#undef PH

  // epilogue: C/D col=lane&15 (n=px), row=quad*4+reg (m=fo); scale by demod
  int h = h0 + wv;
#pragma unroll
  for (int i = 0; i < 8; ++i) {
#pragma unroll
    for (int rr = 0; rr < 4; ++rr) {
      int fo_g = foB * 128 + i * 16 + quad * 4 + rr;
      float dm = dcoef[b * 512 + fo_g];
      float* op = out + ((size_t)((b * 512 + fo_g) * 64 + h)) * 64;
#pragma unroll
      for (int j = 0; j < 4; ++j)
        op[j * 16 + l16] = acc[i][j][rr] * dm;
    }
  }
}

extern "C" void kernel_launch(void* const* d_in, const int* in_sizes, int n_in,
                              void* d_out, int out_size, void* d_ws, size_t ws_size,
                              hipStream_t stream) {
  const float* x     = (const float*)d_in[0];
  const float* style = (const float*)d_in[1];
  const float* w     = (const float*)d_in[2];
  const float* fc_w  = (const float*)d_in[3];
  const float* fc_b  = (const float*)d_in[4];
  float* out = (float*)d_out;
  char* ws = (char*)d_ws;

  float*  s       = (float*)(ws);                  // 16 KB
  float*  dcoef   = (float*)(ws + 16384);          // 16 KB
  float*  wsq     = (float*)(ws + 32768);          // 1 MB
  bf16_t* zerobuf = (bf16_t*)(ws + 1081344);       // 256 B of zeros
  bf16_t* wt      = (bf16_t*)(ws + 1081600);       // 4.5 MB  [tap][g][fo][8]
  bf16_t* xT      = (bf16_t*)(ws + 5800192);       // 32 MB   [b][h][g][w][8]

  k_prep1<<<2049, 256, 0, stream>>>(style, fc_w, fc_b, w, s, wsq, wt, zerobuf);
  k_prep2<<<9216, 256, 0, stream>>>(x, s, wsq, dcoef, xT);
  // grid.x = b -> linear block id % 8 == b -> XCD-pinned batch slice
  k_conv<<<dim3(8, 4, 16), 256, 0, stream>>>(wt, xT, dcoef, zerobuf, out);
}